// Round 2
// baseline (452.811 us; speedup 1.0000x reference)
//
#include <hip/hip_runtime.h>

#define NEG_SLOPE 0.2f

__device__ __forceinline__ float rlane(float v, int l) {
    return __int_as_float(__builtin_amdgcn_readlane(__float_as_int(v), l));
}

// ---------------- CSR build ----------------

__global__ void zero_ints(int* __restrict__ p, int n) {
    int i = blockIdx.x * 256 + threadIdx.x;
    if (i < n) p[i] = 0;
}

__global__ void hist_kernel(const int* __restrict__ dst, int* __restrict__ deg, int E) {
    int i = blockIdx.x * 256 + threadIdx.x;
    if (i < E) atomicAdd(&deg[dst[i]], 1);
}

__global__ void scan_kernel(const int* __restrict__ deg, int* __restrict__ rowptr, int N) {
    __shared__ int sums[1024];
    int t = threadIdx.x;
    int CH = (N + 1023) >> 10;
    int lo = t * CH, hi = min(lo + CH, N);
    int s = 0;
    for (int i = lo; i < hi; ++i) s += deg[i];
    sums[t] = s;
    __syncthreads();
    for (int off = 1; off < 1024; off <<= 1) {
        int v = (t >= off) ? sums[t - off] : 0;
        __syncthreads();
        sums[t] += v;
        __syncthreads();
    }
    int run = (t == 0) ? 0 : sums[t - 1];
    for (int i = lo; i < hi; ++i) { rowptr[i] = run; run += deg[i]; }
    if (t == 1023) rowptr[N] = run;
}

// stores SRC node id (not edge id) grouped by dst
__global__ void fill_kernel(const int* __restrict__ src, const int* __restrict__ dst,
                            const int* __restrict__ rowptr, int* __restrict__ cursor,
                            int* __restrict__ csrc, int E) {
    int i = blockIdx.x * 256 + threadIdx.x;
    if (i < E) {
        int d = dst[i];
        int pos = atomicAdd(&cursor[d], 1);
        csrc[rowptr[d] + pos] = src[i];
    }
}

// ---------------- GEMM: Y[N,OUTF] = X[N,128] @ W[128,OUTF] ----------------

template <int OUTF>
__global__ __launch_bounds__(256) void gemm_kernel(const float* __restrict__ X,
                                                   const float* __restrict__ W,
                                                   float* __restrict__ Y, int N) {
    constexpr int K = 128;
    constexpr int MG = OUTF / 4;          // thread-groups along M
    constexpr int NPB = (256 / MG) * 4;   // nodes per block
    __shared__ float ws[K * OUTF];
    __shared__ float xs[NPB * K];
    int t = threadIdx.x;
    int nbase = blockIdx.x * NPB;

    {   // stage W
        const float4* Wg = (const float4*)W;
        float4* wl = (float4*)ws;
        constexpr int WIT = K * OUTF / 4 / 256;
#pragma unroll
        for (int i = 0; i < WIT; ++i) wl[t + i * 256] = Wg[t + i * 256];
    }
    {   // stage X rows (row-major, 512B-aligned rows)
        const float4* Xg = (const float4*)X;
        float4* xl = (float4*)xs;
        constexpr int XIT = NPB * K / 4 / 256;
#pragma unroll
        for (int i = 0; i < XIT; ++i) {
            int idx = t + i * 256;
            int n = idx >> 5, kq = idx & 31;
            int gn = nbase + n;
            gn = min(gn, N - 1);
            xl[idx] = Xg[(size_t)gn * 32 + kq];
        }
    }
    __syncthreads();

    int mg = t % MG, ngq = t / MG;
    int n0 = ngq * 4;
    float acc[4][4];
#pragma unroll
    for (int i = 0; i < 4; ++i)
#pragma unroll
        for (int j = 0; j < 4; ++j) acc[i][j] = 0.f;

    const float4* xsv = (const float4*)xs;
    const float4* wsv = (const float4*)ws;
    for (int k = 0; k < K; k += 4) {
        float4 xv[4], wv[4];
#pragma unroll
        for (int i = 0; i < 4; ++i) xv[i] = xsv[(n0 + i) * 32 + (k >> 2)];
#pragma unroll
        for (int kk = 0; kk < 4; ++kk) wv[kk] = wsv[(k + kk) * MG + mg];
#pragma unroll
        for (int i = 0; i < 4; ++i) {
#pragma unroll
            for (int kk = 0; kk < 4; ++kk) {
                float xf = ((const float*)&xv[i])[kk];
                acc[i][0] = fmaf(xf, wv[kk].x, acc[i][0]);
                acc[i][1] = fmaf(xf, wv[kk].y, acc[i][1]);
                acc[i][2] = fmaf(xf, wv[kk].z, acc[i][2]);
                acc[i][3] = fmaf(xf, wv[kk].w, acc[i][3]);
            }
        }
    }
    float4* Yg = (float4*)Y;
#pragma unroll
    for (int i = 0; i < 4; ++i) {
        int gn = nbase + n0 + i;
        if (gn < N) {
            float4 r;
            r.x = acc[i][0]; r.y = acc[i][1]; r.z = acc[i][2]; r.w = acc[i][3];
            Yg[(size_t)gn * MG + mg] = r;
        }
    }
}

// ---------------- el/er: per (node, head) dot with a_src/a_dst ----------------

template <int H>
__global__ __launch_bounds__(256) void elr_kernel(const float* __restrict__ feat,
                                                  const float* __restrict__ as_,
                                                  const float* __restrict__ ad_,
                                                  float* __restrict__ el,
                                                  float* __restrict__ er, int N) {
    int task = blockIdx.x * 8 + (threadIdx.x >> 5);  // (n,h) flattened
    int f = threadIdx.x & 31;
    if (task >= N * H) return;
    int h = task % H;
    float v = feat[(size_t)task * 32 + f];
    float s1 = v * as_[h * 32 + f];
    float s2 = v * ad_[h * 32 + f];
#pragma unroll
    for (int off = 16; off >= 1; off >>= 1) {
        s1 += __shfl_xor(s1, off);
        s2 += __shfl_xor(s2, off);
    }
    if (f == 0) { el[task] = s1; er[task] = s2; }
}

// ---------------- aggregation: one wave per dst node ----------------
// out[dst] = (sum_e w_e * feat[src_e]) / (sum_e w_e) + bias,  w_e = exp(lrelu(el[src]+er[dst]))

template <int H, bool DOELU>
__global__ __launch_bounds__(256) void agg_kernel(const float* __restrict__ feat,
                                                  const float* __restrict__ el,
                                                  const float* __restrict__ er,
                                                  const int* __restrict__ rowptr,
                                                  const int* __restrict__ csrc,
                                                  const float* __restrict__ bias,
                                                  float* __restrict__ out, int N) {
    int lane = threadIdx.x & 63;
    int node = blockIdx.x * 4 + (threadIdx.x >> 6);
    if (node >= N) return;
    int row0 = __builtin_amdgcn_readfirstlane(rowptr[node]);
    int row1 = __builtin_amdgcn_readfirstlane(rowptr[node + 1]);

    float ern[H];
    if (H == 4) {
        float4 e4 = ((const float4*)er)[node];
        ern[0] = e4.x; ern[1] = e4.y; ern[2] = e4.z; ern[3] = e4.w;
    } else {
        ern[0] = er[node];
    }

    float dacc[H];
#pragma unroll
    for (int h = 0; h < H; ++h) dacc[h] = 0.f;
    float acc0 = 0.f, acc1 = 0.f;
    int hlo = lane >> 5;

    for (int base = row0; base < row1; base += 64) {
        int e = base + lane;
        int s = 0;
        float w[H];
#pragma unroll
        for (int h = 0; h < H; ++h) w[h] = 0.f;
        if (e < row1) {
            s = csrc[e];
            if (H == 4) {
                float4 l4 = ((const float4*)el)[s];
                float tv[4] = {l4.x + ern[0], l4.y + ern[1], l4.z + ern[2], l4.w + ern[3]};
#pragma unroll
                for (int h = 0; h < 4; ++h) {
                    float tt = tv[h];
                    tt = tt > 0.f ? tt : NEG_SLOPE * tt;
                    w[h] = __expf(tt);
                    dacc[h] += w[h];
                }
            } else {
                float tt = el[s] + ern[0];
                tt = tt > 0.f ? tt : NEG_SLOPE * tt;
                w[0] = __expf(tt);
                dacc[0] += w[0];
            }
        }
        int cnt = min(row1 - base, 64);
        if (H == 4) {
            for (int j = 0; j < cnt; ++j) {
                int sj = __builtin_amdgcn_readlane(s, j);
                float w0 = rlane(w[0], j), w1 = rlane(w[1], j);
                float w2 = rlane(w[2], j), w3 = rlane(w[3], j);
                float wl = hlo ? w1 : w0;
                float wh = hlo ? w3 : w2;
                const float* fp = feat + (size_t)sj * 128;
                acc0 = fmaf(wl, fp[lane], acc0);
                acc1 = fmaf(wh, fp[64 + lane], acc1);
            }
        } else {
            for (int j = 0; j < cnt; ++j) {
                int sj = __builtin_amdgcn_readlane(s, j);
                float w0 = rlane(w[0], j);
                acc0 = fmaf(w0, feat[(size_t)sj * 32 + (lane & 31)], acc0);
            }
        }
    }

#pragma unroll
    for (int h = 0; h < H; ++h) {
#pragma unroll
        for (int off = 1; off < 64; off <<= 1) dacc[h] += __shfl_xor(dacc[h], off);
    }

    if (H == 4) {
        float dlo = hlo ? dacc[1] : dacc[0];
        float dhi = hlo ? dacc[3] : dacc[2];
        float r0 = (row1 > row0) ? acc0 / dlo : 0.f;
        float r1 = (row1 > row0) ? acc1 / dhi : 0.f;
        r0 += bias[lane];
        r1 += bias[64 + lane];
        if (DOELU) {
            r0 = r0 > 0.f ? r0 : __expf(r0) - 1.f;
            r1 = r1 > 0.f ? r1 : __expf(r1) - 1.f;
        }
        out[(size_t)node * 128 + lane] = r0;
        out[(size_t)node * 128 + 64 + lane] = r1;
    } else {
        float r0 = (row1 > row0) ? acc0 / dacc[0] : 0.f;
        r0 += bias[lane & 31];
        if (DOELU) r0 = r0 > 0.f ? r0 : __expf(r0) - 1.f;
        if (lane < 32) out[(size_t)node * 32 + lane] = r0;
    }
}

// ---------------- host ----------------

extern "C" void kernel_launch(void* const* d_in, const int* in_sizes, int n_in,
                              void* d_out, int out_size, void* d_ws, size_t ws_size,
                              hipStream_t stream) {
    const float* features = (const float*)d_in[0];
    const int* esrc = (const int*)d_in[1];
    const int* edst = (const int*)d_in[2];
    const float* W1 = (const float*)d_in[3];
    const float* a1s = (const float*)d_in[4];
    const float* a1d = (const float*)d_in[5];
    const float* b1 = (const float*)d_in[6];
    const float* W2 = (const float*)d_in[7];
    const float* a2s = (const float*)d_in[8];
    const float* a2d = (const float*)d_in[9];
    const float* b2 = (const float*)d_in[10];
    const float* W3 = (const float*)d_in[11];
    const float* a3s = (const float*)d_in[12];
    const float* a3d = (const float*)d_in[13];
    const float* b3 = (const float*)d_in[14];

    int N = in_sizes[0] / 128;
    int E = in_sizes[1];

    char* base = (char*)d_ws;
    size_t off = 0;
    auto nxt = [&](size_t bytes) {
        void* p = base + off;
        off += (bytes + 255) & ~(size_t)255;
        return p;
    };
    float* A = (float*)nxt((size_t)N * 128 * 4);   // feat
    float* B = (float*)nxt((size_t)N * 128 * 4);   // layer activations
    float* el = (float*)nxt((size_t)N * 4 * 4);
    float* er = (float*)nxt((size_t)N * 4 * 4);
    int* deg = (int*)nxt((size_t)N * 2 * 4);       // deg + cursor contiguous
    int* cursor = deg + N;
    int* rowptr = (int*)nxt((size_t)(N + 1) * 4);
    int* csrc = (int*)nxt((size_t)E * 4);

    // CSR build (same graph for all 3 layers)
    zero_ints<<<(2 * N + 255) / 256, 256, 0, stream>>>(deg, 2 * N);
    hist_kernel<<<(E + 255) / 256, 256, 0, stream>>>(edst, deg, E);
    scan_kernel<<<1, 1024, 0, stream>>>(deg, rowptr, N);
    fill_kernel<<<(E + 255) / 256, 256, 0, stream>>>(esrc, edst, rowptr, cursor, csrc, E);

    // layer 1: 128 -> 4x32, ELU
    gemm_kernel<128><<<(N + 31) / 32, 256, 0, stream>>>(features, W1, A, N);
    elr_kernel<4><<<(N * 4 + 7) / 8, 256, 0, stream>>>(A, a1s, a1d, el, er, N);
    agg_kernel<4, true><<<(N + 3) / 4, 256, 0, stream>>>(A, el, er, rowptr, csrc, b1, B, N);

    // layer 2: 128 -> 4x32, ELU
    gemm_kernel<128><<<(N + 31) / 32, 256, 0, stream>>>(B, W2, A, N);
    elr_kernel<4><<<(N * 4 + 7) / 8, 256, 0, stream>>>(A, a2s, a2d, el, er, N);
    agg_kernel<4, true><<<(N + 3) / 4, 256, 0, stream>>>(A, el, er, rowptr, csrc, b2, B, N);

    // layer 3: 128 -> 1x32, no ELU, mean over 1 head = identity
    gemm_kernel<32><<<(N + 127) / 128, 256, 0, stream>>>(B, W3, A, N);
    elr_kernel<1><<<(N + 7) / 8, 256, 0, stream>>>(A, a3s, a3d, el, er, N);
    agg_kernel<1, false><<<(N + 3) / 4, 256, 0, stream>>>(A, el, er, rowptr, csrc, b3,
                                                          (float*)d_out, N);
}

// Round 7
// 349.838 us; speedup vs baseline: 1.2943x; 1.2943x over previous
//
#include <hip/hip_runtime.h>

#define NEG_SLOPE 0.2f

__device__ __forceinline__ float bperm_f(int idx, float v) {
    return __int_as_float(__builtin_amdgcn_ds_bpermute(idx, __float_as_int(v)));
}

// ---------------- CSR build ----------------

__global__ void zero_ints(int* __restrict__ p, int n) {
    int i = blockIdx.x * 256 + threadIdx.x;
    if (i < n) p[i] = 0;
}

__global__ void hist_kernel(const int* __restrict__ dst, int* __restrict__ deg, int E) {
    int i = blockIdx.x * 256 + threadIdx.x;
    if (i < E) atomicAdd(&deg[dst[i]], 1);
}

// 3-kernel parallel exclusive scan of deg[N] -> rowptr[N+1]
#define SCAN_CH 2048

__global__ __launch_bounds__(256) void scan_blocksum(const int* __restrict__ deg,
                                                     int* __restrict__ bsum, int N) {
    int blk = blockIdx.x, t = threadIdx.x;
    int base = blk * SCAN_CH;
    int s = 0;
#pragma unroll
    for (int i = 0; i < SCAN_CH / 256; ++i) {
        int idx = base + t + i * 256;
        if (idx < N) s += deg[idx];
    }
#pragma unroll
    for (int off = 1; off < 64; off <<= 1) s += __shfl_xor(s, off);
    __shared__ int wt[4];
    if ((t & 63) == 0) wt[t >> 6] = s;
    __syncthreads();
    if (t == 0) bsum[blk] = wt[0] + wt[1] + wt[2] + wt[3];
}

__global__ void scan_bsum(const int* __restrict__ bsum, int* __restrict__ boff, int nb) {
    int t = threadIdx.x;
    int orig = (t < nb) ? bsum[t] : 0;
    int v = orig;
#pragma unroll
    for (int off = 1; off < 64; off <<= 1) {
        int u = __shfl_up(v, off);
        if (t >= off) v += u;
    }
    if (t < nb) boff[t] = v - orig;
}

__global__ __launch_bounds__(256) void scan_write(const int* __restrict__ deg,
                                                  const int* __restrict__ boff,
                                                  int* __restrict__ rowptr, int N) {
    int blk = blockIdx.x, t = threadIdx.x;
    int base = blk * SCAN_CH + t * 8;
    int v[8];
    int s = 0;
#pragma unroll
    for (int r = 0; r < 8; ++r) {
        int idx = base + r;
        v[r] = (idx < N) ? deg[idx] : 0;
        s += v[r];
    }
    int lane = t & 63, wid = t >> 6;
    int p = s;
#pragma unroll
    for (int off = 1; off < 64; off <<= 1) {
        int u = __shfl_up(p, off);
        if (lane >= off) p += u;
    }
    __shared__ int wtot[4];
    if (lane == 63) wtot[wid] = p;
    __syncthreads();
    int run = boff[blk];
    for (int w = 0; w < wid; ++w) run += wtot[w];
    run += p - s;
#pragma unroll
    for (int r = 0; r < 8; ++r) {
        int idx = base + r;
        if (idx < N) {
            rowptr[idx] = run;
            run += v[r];
            if (idx == N - 1) rowptr[N] = run;
        }
    }
}

// stores SRC node id (not edge id) grouped by dst
__global__ void fill_kernel(const int* __restrict__ src, const int* __restrict__ dst,
                            const int* __restrict__ rowptr, int* __restrict__ cursor,
                            int* __restrict__ csrc, int E) {
    int i = blockIdx.x * 256 + threadIdx.x;
    if (i < E) {
        int d = dst[i];
        int pos = atomicAdd(&cursor[d], 1);
        csrc[rowptr[d] + pos] = src[i];
    }
}

// ---------------- GEMM: Y[N,OUTF] = X[N,128] @ W[128,OUTF] ----------------

template <int OUTF>
__global__ __launch_bounds__(256) void gemm_kernel(const float* __restrict__ X,
                                                   const float* __restrict__ W,
                                                   float* __restrict__ Y, int N) {
    constexpr int K = 128;
    constexpr int MG = OUTF / 4;          // thread-groups along M
    constexpr int NPB = (256 / MG) * 4;   // nodes per block
    __shared__ float ws[K * OUTF];
    __shared__ float xs[NPB * K];
    int t = threadIdx.x;
    int nbase = blockIdx.x * NPB;

    {   // stage W
        const float4* Wg = (const float4*)W;
        float4* wl = (float4*)ws;
        constexpr int WIT = K * OUTF / 4 / 256;
#pragma unroll
        for (int i = 0; i < WIT; ++i) wl[t + i * 256] = Wg[t + i * 256];
    }
    {   // stage X rows
        const float4* Xg = (const float4*)X;
        float4* xl = (float4*)xs;
        constexpr int XIT = NPB * K / 4 / 256;
#pragma unroll
        for (int i = 0; i < XIT; ++i) {
            int idx = t + i * 256;
            int n = idx >> 5, kq = idx & 31;
            int gn = nbase + n;
            gn = min(gn, N - 1);
            xl[idx] = Xg[(size_t)gn * 32 + kq];
        }
    }
    __syncthreads();

    int mg = t % MG, ngq = t / MG;
    int n0 = ngq * 4;
    float acc[4][4];
#pragma unroll
    for (int i = 0; i < 4; ++i)
#pragma unroll
        for (int j = 0; j < 4; ++j) acc[i][j] = 0.f;

    const float4* xsv = (const float4*)xs;
    const float4* wsv = (const float4*)ws;
    for (int k = 0; k < K; k += 4) {
        float4 xv[4], wv[4];
#pragma unroll
        for (int i = 0; i < 4; ++i) xv[i] = xsv[(n0 + i) * 32 + (k >> 2)];
#pragma unroll
        for (int kk = 0; kk < 4; ++kk) wv[kk] = wsv[(k + kk) * MG + mg];
#pragma unroll
        for (int i = 0; i < 4; ++i) {
#pragma unroll
            for (int kk = 0; kk < 4; ++kk) {
                float xf = ((const float*)&xv[i])[kk];
                acc[i][0] = fmaf(xf, wv[kk].x, acc[i][0]);
                acc[i][1] = fmaf(xf, wv[kk].y, acc[i][1]);
                acc[i][2] = fmaf(xf, wv[kk].z, acc[i][2]);
                acc[i][3] = fmaf(xf, wv[kk].w, acc[i][3]);
            }
        }
    }
    float4* Yg = (float4*)Y;
#pragma unroll
    for (int i = 0; i < 4; ++i) {
        int gn = nbase + n0 + i;
        if (gn < N) {
            float4 r;
            r.x = acc[i][0]; r.y = acc[i][1]; r.z = acc[i][2]; r.w = acc[i][3];
            Yg[(size_t)gn * MG + mg] = r;
        }
    }
}

// ---------------- el/er ----------------

template <int H>
__global__ __launch_bounds__(256) void elr_kernel(const float* __restrict__ feat,
                                                  const float* __restrict__ as_,
                                                  const float* __restrict__ ad_,
                                                  float* __restrict__ el,
                                                  float* __restrict__ er, int N) {
    int task = blockIdx.x * 8 + (threadIdx.x >> 5);  // (n,h) flattened
    int f = threadIdx.x & 31;
    if (task >= N * H) return;
    int h = task % H;
    float v = feat[(size_t)task * 32 + f];
    float s1 = v * as_[h * 32 + f];
    float s2 = v * ad_[h * 32 + f];
#pragma unroll
    for (int off = 16; off >= 1; off >>= 1) {
        s1 += __shfl_xor(s1, off);
        s2 += __shfl_xor(s2, off);
    }
    if (f == 0) { el[task] = s1; er[task] = s2; }
}

// ---------------- aggregation (H=4): one wave per dst node ----------------
// 4 groups of 16 lanes; group g handles edge it*4+g; lane covers 8 feats.

template <bool DOELU>
__global__ __launch_bounds__(256) void agg4_kernel(const float* __restrict__ feat,
                                                   const float* __restrict__ el,
                                                   const float* __restrict__ er,
                                                   const int* __restrict__ rowptr,
                                                   const int* __restrict__ csrc,
                                                   const float* __restrict__ bias,
                                                   float* __restrict__ out, int N) {
    int lane = threadIdx.x & 63;
    int node = blockIdx.x * 4 + (threadIdx.x >> 6);
    if (node >= N) return;
    int row0 = __builtin_amdgcn_readfirstlane(rowptr[node]);
    int row1 = __builtin_amdgcn_readfirstlane(rowptr[node + 1]);

    float4 e4 = ((const float4*)er)[node];
    float ern0 = e4.x, ern1 = e4.y, ern2 = e4.z, ern3 = e4.w;

    int g = lane >> 4;        // edge group
    int li = lane & 15;       // lane within group: feats li*8..li*8+7
    int h = li >> 2;          // head owning those feats

    float dacc0 = 0.f, dacc1 = 0.f, dacc2 = 0.f, dacc3 = 0.f;
    float acc[8];
#pragma unroll
    for (int r = 0; r < 8; ++r) acc[r] = 0.f;

    for (int base = row0; base < row1; base += 64) {
        int e = base + lane;
        int s = 0;
        float w0 = 0.f, w1 = 0.f, w2 = 0.f, w3 = 0.f;
        if (e < row1) {
            s = csrc[e];
            float4 l4 = ((const float4*)el)[s];
            float t0 = l4.x + ern0; t0 = t0 > 0.f ? t0 : NEG_SLOPE * t0; w0 = __expf(t0);
            float t1 = l4.y + ern1; t1 = t1 > 0.f ? t1 : NEG_SLOPE * t1; w1 = __expf(t1);
            float t2 = l4.z + ern2; t2 = t2 > 0.f ? t2 : NEG_SLOPE * t2; w2 = __expf(t2);
            float t3 = l4.w + ern3; t3 = t3 > 0.f ? t3 : NEG_SLOPE * t3; w3 = __expf(t3);
            dacc0 += w0; dacc1 += w1; dacc2 += w2; dacc3 += w3;
        }
        int cnt = min(row1 - base, 64);
        int iters = (cnt + 3) >> 2;
        for (int it = 0; it < iters; ++it) {
            int idx = ((it << 2) + g) << 2;
            int sj = __builtin_amdgcn_ds_bpermute(idx, s);
            float a0 = bperm_f(idx, w0), a1 = bperm_f(idx, w1);
            float a2 = bperm_f(idx, w2), a3 = bperm_f(idx, w3);
            float wa = (h & 1) ? a1 : a0;
            float wb = (h & 1) ? a3 : a2;
            float wsel = (h & 2) ? wb : wa;
            const float4* fp = (const float4*)(feat + (size_t)sj * 128) + li * 2;
            float4 v0 = fp[0], v1 = fp[1];
            acc[0] = fmaf(wsel, v0.x, acc[0]);
            acc[1] = fmaf(wsel, v0.y, acc[1]);
            acc[2] = fmaf(wsel, v0.z, acc[2]);
            acc[3] = fmaf(wsel, v0.w, acc[3]);
            acc[4] = fmaf(wsel, v1.x, acc[4]);
            acc[5] = fmaf(wsel, v1.y, acc[5]);
            acc[6] = fmaf(wsel, v1.z, acc[6]);
            acc[7] = fmaf(wsel, v1.w, acc[7]);
        }
    }

    // reduce partial rows across the 4 edge-groups (stride 16, 32)
#pragma unroll
    for (int r = 0; r < 8; ++r) {
        acc[r] += __shfl_xor(acc[r], 16);
        acc[r] += __shfl_xor(acc[r], 32);
    }
    // denominators: full-wave butterfly
#pragma unroll
    for (int off = 1; off < 64; off <<= 1) {
        dacc0 += __shfl_xor(dacc0, off);
        dacc1 += __shfl_xor(dacc1, off);
        dacc2 += __shfl_xor(dacc2, off);
        dacc3 += __shfl_xor(dacc3, off);
    }

    if (lane < 16) {
        float da = (h & 1) ? dacc1 : dacc0;
        float db = (h & 1) ? dacc3 : dacc2;
        float d = (h & 2) ? db : da;
        float inv = (row1 > row0) ? 1.f / d : 0.f;
        const float4* bv = (const float4*)bias + lane * 2;
        float4 b0 = bv[0], b1 = bv[1];
        float o[8];
#pragma unroll
        for (int r = 0; r < 8; ++r) o[r] = acc[r] * inv;
        o[0] += b0.x; o[1] += b0.y; o[2] += b0.z; o[3] += b0.w;
        o[4] += b1.x; o[5] += b1.y; o[6] += b1.z; o[7] += b1.w;
        if (DOELU) {
#pragma unroll
            for (int r = 0; r < 8; ++r) o[r] = o[r] > 0.f ? o[r] : __expf(o[r]) - 1.f;
        }
        float4 q0, q1;
        q0.x = o[0]; q0.y = o[1]; q0.z = o[2]; q0.w = o[3];
        q1.x = o[4]; q1.y = o[5]; q1.z = o[6]; q1.w = o[7];
        float4* ov = (float4*)(out + (size_t)node * 128) + lane * 2;
        ov[0] = q0;
        ov[1] = q1;
    }
}

// ---------------- aggregation (H=1): one wave per dst node ----------------
// 8 groups of 8 lanes; group g handles edge it*8+g; lane covers 4 feats.

__global__ __launch_bounds__(256) void agg1_kernel(const float* __restrict__ feat,
                                                   const float* __restrict__ el,
                                                   const float* __restrict__ er,
                                                   const int* __restrict__ rowptr,
                                                   const int* __restrict__ csrc,
                                                   const float* __restrict__ bias,
                                                   float* __restrict__ out, int N) {
    int lane = threadIdx.x & 63;
    int node = blockIdx.x * 4 + (threadIdx.x >> 6);
    if (node >= N) return;
    int row0 = __builtin_amdgcn_readfirstlane(rowptr[node]);
    int row1 = __builtin_amdgcn_readfirstlane(rowptr[node + 1]);

    float ern = er[node];
    int g = lane >> 3;
    int li = lane & 7;

    float dacc = 0.f;
    float acc[4];
#pragma unroll
    for (int r = 0; r < 4; ++r) acc[r] = 0.f;

    for (int base = row0; base < row1; base += 64) {
        int e = base + lane;
        int s = 0;
        float w0 = 0.f;
        if (e < row1) {
            s = csrc[e];
            float t0 = el[s] + ern;
            t0 = t0 > 0.f ? t0 : NEG_SLOPE * t0;
            w0 = __expf(t0);
            dacc += w0;
        }
        int cnt = min(row1 - base, 64);
        int iters = (cnt + 7) >> 3;
        for (int it = 0; it < iters; ++it) {
            int idx = ((it << 3) + g) << 2;
            int sj = __builtin_amdgcn_ds_bpermute(idx, s);
            float wsel = bperm_f(idx, w0);
            const float4* fp = (const float4*)(feat + (size_t)sj * 32) + li;
            float4 v0 = fp[0];
            acc[0] = fmaf(wsel, v0.x, acc[0]);
            acc[1] = fmaf(wsel, v0.y, acc[1]);
            acc[2] = fmaf(wsel, v0.z, acc[2]);
            acc[3] = fmaf(wsel, v0.w, acc[3]);
        }
    }

#pragma unroll
    for (int r = 0; r < 4; ++r) {
        acc[r] += __shfl_xor(acc[r], 8);
        acc[r] += __shfl_xor(acc[r], 16);
        acc[r] += __shfl_xor(acc[r], 32);
    }
#pragma unroll
    for (int off = 1; off < 64; off <<= 1) dacc += __shfl_xor(dacc, off);

    if (lane < 8) {
        float inv = (row1 > row0) ? 1.f / dacc : 0.f;
        float4 b0 = ((const float4*)bias)[lane];
        float4 q;
        q.x = acc[0] * inv + b0.x;
        q.y = acc[1] * inv + b0.y;
        q.z = acc[2] * inv + b0.z;
        q.w = acc[3] * inv + b0.w;
        ((float4*)(out + (size_t)node * 32))[lane] = q;
    }
}

// ---------------- host ----------------

extern "C" void kernel_launch(void* const* d_in, const int* in_sizes, int n_in,
                              void* d_out, int out_size, void* d_ws, size_t ws_size,
                              hipStream_t stream) {
    const float* features = (const float*)d_in[0];
    const int* esrc = (const int*)d_in[1];
    const int* edst = (const int*)d_in[2];
    const float* W1 = (const float*)d_in[3];
    const float* a1s = (const float*)d_in[4];
    const float* a1d = (const float*)d_in[5];
    const float* b1 = (const float*)d_in[6];
    const float* W2 = (const float*)d_in[7];
    const float* a2s = (const float*)d_in[8];
    const float* a2d = (const float*)d_in[9];
    const float* b2 = (const float*)d_in[10];
    const float* W3 = (const float*)d_in[11];
    const float* a3s = (const float*)d_in[12];
    const float* a3d = (const float*)d_in[13];
    const float* b3 = (const float*)d_in[14];

    int N = in_sizes[0] / 128;
    int E = in_sizes[1];
    int nb = (N + SCAN_CH - 1) / SCAN_CH;

    char* base = (char*)d_ws;
    size_t off = 0;
    auto nxt = [&](size_t bytes) {
        void* p = base + off;
        off += (bytes + 255) & ~(size_t)255;
        return p;
    };
    float* A = (float*)nxt((size_t)N * 128 * 4);   // feat
    float* B = (float*)nxt((size_t)N * 128 * 4);   // layer activations
    float* el = (float*)nxt((size_t)N * 4 * 4);
    float* er = (float*)nxt((size_t)N * 4 * 4);
    int* deg = (int*)nxt((size_t)N * 2 * 4);       // deg + cursor contiguous
    int* cursor = deg + N;
    int* rowptr = (int*)nxt((size_t)(N + 1) * 4);
    int* csrc = (int*)nxt((size_t)E * 4);
    int* bsum = (int*)nxt((size_t)(nb + 1) * 4);
    int* boff = (int*)nxt((size_t)(nb + 1) * 4);

    // CSR build (same graph for all 3 layers)
    zero_ints<<<(2 * N + 255) / 256, 256, 0, stream>>>(deg, 2 * N);
    hist_kernel<<<(E + 255) / 256, 256, 0, stream>>>(edst, deg, E);
    scan_blocksum<<<nb, 256, 0, stream>>>(deg, bsum, N);
    scan_bsum<<<1, 64, 0, stream>>>(bsum, boff, nb);
    scan_write<<<nb, 256, 0, stream>>>(deg, boff, rowptr, N);
    fill_kernel<<<(E + 255) / 256, 256, 0, stream>>>(esrc, edst, rowptr, cursor, csrc, E);

    // layer 1: 128 -> 4x32, ELU
    gemm_kernel<128><<<(N + 31) / 32, 256, 0, stream>>>(features, W1, A, N);
    elr_kernel<4><<<(N * 4 + 7) / 8, 256, 0, stream>>>(A, a1s, a1d, el, er, N);
    agg4_kernel<true><<<(N + 3) / 4, 256, 0, stream>>>(A, el, er, rowptr, csrc, b1, B, N);

    // layer 2: 128 -> 4x32, ELU
    gemm_kernel<128><<<(N + 31) / 32, 256, 0, stream>>>(B, W2, A, N);
    elr_kernel<4><<<(N * 4 + 7) / 8, 256, 0, stream>>>(A, a2s, a2d, el, er, N);
    agg4_kernel<true><<<(N + 3) / 4, 256, 0, stream>>>(A, el, er, rowptr, csrc, b2, B, N);

    // layer 3: 128 -> 1x32, no ELU, mean over 1 head = identity
    gemm_kernel<32><<<(N + 127) / 128, 256, 0, stream>>>(B, W3, A, N);
    elr_kernel<1><<<(N + 7) / 8, 256, 0, stream>>>(A, a3s, a3d, el, er, N);
    agg1_kernel<<<(N + 3) / 4, 256, 0, stream>>>(A, el, er, rowptr, csrc, b3,
                                                 (float*)d_out, N);
}

// Round 8
// 318.516 us; speedup vs baseline: 1.4216x; 1.0983x over previous
//
#include <hip/hip_runtime.h>

#define NEG_SLOPE 0.2f

__device__ __forceinline__ float bperm_f(int idx, float v) {
    return __int_as_float(__builtin_amdgcn_ds_bpermute(idx, __float_as_int(v)));
}

// ---------------- CSR build ----------------

__global__ void zero_ints(int* __restrict__ p, int n) {
    int i = blockIdx.x * 256 + threadIdx.x;
    if (i < n) p[i] = 0;
}

__global__ void hist_kernel(const int* __restrict__ dst, int* __restrict__ deg, int E) {
    int i = blockIdx.x * 256 + threadIdx.x;
    if (i < E) atomicAdd(&deg[dst[i]], 1);
}

#define SCAN_CH 2048

__global__ __launch_bounds__(256) void scan_blocksum(const int* __restrict__ deg,
                                                     int* __restrict__ bsum, int N) {
    int blk = blockIdx.x, t = threadIdx.x;
    int base = blk * SCAN_CH;
    int s = 0;
#pragma unroll
    for (int i = 0; i < SCAN_CH / 256; ++i) {
        int idx = base + t + i * 256;
        if (idx < N) s += deg[idx];
    }
#pragma unroll
    for (int off = 1; off < 64; off <<= 1) s += __shfl_xor(s, off);
    __shared__ int wt[4];
    if ((t & 63) == 0) wt[t >> 6] = s;
    __syncthreads();
    if (t == 0) bsum[blk] = wt[0] + wt[1] + wt[2] + wt[3];
}

__global__ void scan_bsum(const int* __restrict__ bsum, int* __restrict__ boff, int nb) {
    int t = threadIdx.x;
    int orig = (t < nb) ? bsum[t] : 0;
    int v = orig;
#pragma unroll
    for (int off = 1; off < 64; off <<= 1) {
        int u = __shfl_up(v, off);
        if (t >= off) v += u;
    }
    if (t < nb) boff[t] = v - orig;
}

__global__ __launch_bounds__(256) void scan_write(const int* __restrict__ deg,
                                                  const int* __restrict__ boff,
                                                  int* __restrict__ rowptr, int N) {
    int blk = blockIdx.x, t = threadIdx.x;
    int base = blk * SCAN_CH + t * 8;
    int v[8];
    int s = 0;
#pragma unroll
    for (int r = 0; r < 8; ++r) {
        int idx = base + r;
        v[r] = (idx < N) ? deg[idx] : 0;
        s += v[r];
    }
    int lane = t & 63, wid = t >> 6;
    int p = s;
#pragma unroll
    for (int off = 1; off < 64; off <<= 1) {
        int u = __shfl_up(p, off);
        if (lane >= off) p += u;
    }
    __shared__ int wtot[4];
    if (lane == 63) wtot[wid] = p;
    __syncthreads();
    int run = boff[blk];
    for (int w = 0; w < wid; ++w) run += wtot[w];
    run += p - s;
#pragma unroll
    for (int r = 0; r < 8; ++r) {
        int idx = base + r;
        if (idx < N) {
            rowptr[idx] = run;
            run += v[r];
            if (idx == N - 1) rowptr[N] = run;
        }
    }
}

__global__ void fill_kernel(const int* __restrict__ src, const int* __restrict__ dst,
                            const int* __restrict__ rowptr, int* __restrict__ cursor,
                            int* __restrict__ csrc, int E) {
    int i = blockIdx.x * 256 + threadIdx.x;
    if (i < E) {
        int d = dst[i];
        int pos = atomicAdd(&cursor[d], 1);
        csrc[rowptr[d] + pos] = src[i];
    }
}

// -------- GEMM + fused el/er: Y = X@W;  el/er = (Y reshaped).dot(a_s/a_d) --------

template <int OUTF>
__global__ __launch_bounds__(256) void gemm_kernel(const float* __restrict__ X,
                                                   const float* __restrict__ W,
                                                   float* __restrict__ Y,
                                                   const float* __restrict__ as_,
                                                   const float* __restrict__ ad_,
                                                   float* __restrict__ el,
                                                   float* __restrict__ er, int N) {
    constexpr int K = 128;
    constexpr int MG = OUTF / 4;          // thread-groups along M
    constexpr int NPB = (256 / MG) * 4;   // nodes per block
    constexpr int H = OUTF / 32;          // heads
    __shared__ float ws[K * OUTF];
    __shared__ float xs[NPB * K];
    int t = threadIdx.x;
    int nbase = blockIdx.x * NPB;

    {   // stage W
        const float4* Wg = (const float4*)W;
        float4* wl = (float4*)ws;
        constexpr int WIT = K * OUTF / 4 / 256;
#pragma unroll
        for (int i = 0; i < WIT; ++i) wl[t + i * 256] = Wg[t + i * 256];
    }
    {   // stage X rows
        const float4* Xg = (const float4*)X;
        float4* xl = (float4*)xs;
        constexpr int XIT = NPB * K / 4 / 256;
#pragma unroll
        for (int i = 0; i < XIT; ++i) {
            int idx = t + i * 256;
            int n = idx >> 5, kq = idx & 31;
            int gn = nbase + n;
            gn = min(gn, N - 1);
            xl[idx] = Xg[(size_t)gn * 32 + kq];
        }
    }
    __syncthreads();

    int mg = t % MG, ngq = t / MG;
    int n0 = ngq * 4;
    float acc[4][4];
#pragma unroll
    for (int i = 0; i < 4; ++i)
#pragma unroll
        for (int j = 0; j < 4; ++j) acc[i][j] = 0.f;

    const float4* xsv = (const float4*)xs;
    const float4* wsv = (const float4*)ws;
    for (int k = 0; k < K; k += 4) {
        float4 xv[4], wv[4];
#pragma unroll
        for (int i = 0; i < 4; ++i) xv[i] = xsv[(n0 + i) * 32 + (k >> 2)];
#pragma unroll
        for (int kk = 0; kk < 4; ++kk) wv[kk] = wsv[(k + kk) * MG + mg];
#pragma unroll
        for (int i = 0; i < 4; ++i) {
#pragma unroll
            for (int kk = 0; kk < 4; ++kk) {
                float xf = ((const float*)&xv[i])[kk];
                acc[i][0] = fmaf(xf, wv[kk].x, acc[i][0]);
                acc[i][1] = fmaf(xf, wv[kk].y, acc[i][1]);
                acc[i][2] = fmaf(xf, wv[kk].z, acc[i][2]);
                acc[i][3] = fmaf(xf, wv[kk].w, acc[i][3]);
            }
        }
    }

    // fused attention logits: head h = mg/8 (H=4) or 0 (H=1)
    int h = mg >> 3;  // valid for OUTF=128; for OUTF=32, mg<8 -> h=0
    if (OUTF == 32) h = 0;
    float4 as4 = ((const float4*)as_)[mg];
    float4 ad4 = ((const float4*)ad_)[mg];

    float4* Yg = (float4*)Y;
#pragma unroll
    for (int i = 0; i < 4; ++i) {
        int gn = nbase + n0 + i;
        float pel = acc[i][0] * as4.x + acc[i][1] * as4.y + acc[i][2] * as4.z +
                    acc[i][3] * as4.w;
        float per = acc[i][0] * ad4.x + acc[i][1] * ad4.y + acc[i][2] * ad4.z +
                    acc[i][3] * ad4.w;
#pragma unroll
        for (int off = 1; off < 8; off <<= 1) {
            pel += __shfl_xor(pel, off);
            per += __shfl_xor(per, off);
        }
        if (gn < N) {
            float4 r;
            r.x = acc[i][0]; r.y = acc[i][1]; r.z = acc[i][2]; r.w = acc[i][3];
            Yg[(size_t)gn * MG + mg] = r;
            if ((mg & 7) == 0) {
                el[gn * H + h] = pel;
                er[gn * H + h] = per;
            }
        }
    }
}

// ---------------- aggregation (H=4): one wave per dst node ----------------
// Weight phase: 16-edge batches, lane m handles edge m>>2, head m&3 (1 exp/lane).
// Gather: 4 groups of 16 lanes; group g takes edge it*4+g; lane covers 8 feats.
// Single bpermute index (src lane = ep*4+h) serves both sj and wsel.

template <bool DOELU>
__global__ __launch_bounds__(256) void agg4_kernel(const float* __restrict__ feat,
                                                   const float* __restrict__ el,
                                                   const float* __restrict__ er,
                                                   const int* __restrict__ rowptr,
                                                   const int* __restrict__ csrc,
                                                   const float* __restrict__ bias,
                                                   float* __restrict__ out, int N) {
    int lane = threadIdx.x & 63;
    int node = blockIdx.x * 4 + (threadIdx.x >> 6);
    if (node >= N) return;
    int row0 = __builtin_amdgcn_readfirstlane(rowptr[node]);
    int row1 = __builtin_amdgcn_readfirstlane(rowptr[node + 1]);

    int qe = lane >> 2;       // edge slot in 16-edge batch
    int qh = lane & 3;        // head for weight phase
    float ern = er[node * 4 + qh];

    int g = lane >> 4;        // gather group
    int li = lane & 15;       // lane in group: feats li*8..li*8+7
    int h = li >> 2;          // head owning those feats

    float dacc = 0.f;         // per-lane partial denom of head qh
    float acc[8];
#pragma unroll
    for (int r = 0; r < 8; ++r) acc[r] = 0.f;

    for (int base = row0; base < row1; base += 16) {
        int e = base + qe;
        int s = 0;
        float w = 0.f;
        if (e < row1) {
            s = csrc[e];
            float tt = el[s * 4 + qh] + ern;
            tt = tt > 0.f ? tt : NEG_SLOPE * tt;
            w = __expf(tt);
            dacc += w;
        }
        int cnt = min(row1 - base, 16);
        int iters = (cnt + 3) >> 2;
        int it = 0;
        for (; it + 1 < iters; it += 2) {
            int idxA = ((((it << 2) + g) << 2) + h) << 2;
            int idxB = (((((it + 1) << 2) + g) << 2) + h) << 2;
            int sjA = __builtin_amdgcn_ds_bpermute(idxA, s);
            float wA = bperm_f(idxA, w);
            int sjB = __builtin_amdgcn_ds_bpermute(idxB, s);
            float wB = bperm_f(idxB, w);
            const float4* fpA = (const float4*)(feat + (size_t)sjA * 128) + li * 2;
            const float4* fpB = (const float4*)(feat + (size_t)sjB * 128) + li * 2;
            float4 a0 = fpA[0], a1 = fpA[1];
            float4 b0 = fpB[0], b1 = fpB[1];
            acc[0] = fmaf(wA, a0.x, acc[0]); acc[1] = fmaf(wA, a0.y, acc[1]);
            acc[2] = fmaf(wA, a0.z, acc[2]); acc[3] = fmaf(wA, a0.w, acc[3]);
            acc[4] = fmaf(wA, a1.x, acc[4]); acc[5] = fmaf(wA, a1.y, acc[5]);
            acc[6] = fmaf(wA, a1.z, acc[6]); acc[7] = fmaf(wA, a1.w, acc[7]);
            acc[0] = fmaf(wB, b0.x, acc[0]); acc[1] = fmaf(wB, b0.y, acc[1]);
            acc[2] = fmaf(wB, b0.z, acc[2]); acc[3] = fmaf(wB, b0.w, acc[3]);
            acc[4] = fmaf(wB, b1.x, acc[4]); acc[5] = fmaf(wB, b1.y, acc[5]);
            acc[6] = fmaf(wB, b1.z, acc[6]); acc[7] = fmaf(wB, b1.w, acc[7]);
        }
        if (it < iters) {
            int idx = ((((it << 2) + g) << 2) + h) << 2;
            int sj = __builtin_amdgcn_ds_bpermute(idx, s);
            float wsel = bperm_f(idx, w);
            const float4* fp = (const float4*)(feat + (size_t)sj * 128) + li * 2;
            float4 v0 = fp[0], v1 = fp[1];
            acc[0] = fmaf(wsel, v0.x, acc[0]); acc[1] = fmaf(wsel, v0.y, acc[1]);
            acc[2] = fmaf(wsel, v0.z, acc[2]); acc[3] = fmaf(wsel, v0.w, acc[3]);
            acc[4] = fmaf(wsel, v1.x, acc[4]); acc[5] = fmaf(wsel, v1.y, acc[5]);
            acc[6] = fmaf(wsel, v1.z, acc[6]); acc[7] = fmaf(wsel, v1.w, acc[7]);
        }
    }

    // reduce partial rows across the 4 gather groups
#pragma unroll
    for (int r = 0; r < 8; ++r) {
        acc[r] += __shfl_xor(acc[r], 16);
        acc[r] += __shfl_xor(acc[r], 32);
    }
    // denominator: sum over all lanes sharing the same head (lane&3)
#pragma unroll
    for (int off = 4; off < 64; off <<= 1) dacc += __shfl_xor(dacc, off);
    // output lane li needs denom of head li>>2 (lives on lane li>>2 among others)
    float d = bperm_f((li >> 2) << 2, dacc);

    if (lane < 16) {
        float inv = (row1 > row0) ? 1.f / d : 0.f;
        const float4* bv = (const float4*)bias + li * 2;
        float4 b0 = bv[0], b1 = bv[1];
        float o[8];
#pragma unroll
        for (int r = 0; r < 8; ++r) o[r] = acc[r] * inv;
        o[0] += b0.x; o[1] += b0.y; o[2] += b0.z; o[3] += b0.w;
        o[4] += b1.x; o[5] += b1.y; o[6] += b1.z; o[7] += b1.w;
        if (DOELU) {
#pragma unroll
            for (int r = 0; r < 8; ++r) o[r] = o[r] > 0.f ? o[r] : __expf(o[r]) - 1.f;
        }
        float4 q0, q1;
        q0.x = o[0]; q0.y = o[1]; q0.z = o[2]; q0.w = o[3];
        q1.x = o[4]; q1.y = o[5]; q1.z = o[6]; q1.w = o[7];
        float4* ov = (float4*)(out + (size_t)node * 128) + li * 2;
        ov[0] = q0;
        ov[1] = q1;
    }
}

// ---------------- aggregation (H=1): one wave per dst node ----------------
// 64-edge batches; 8 groups of 8 lanes; 2x unrolled pipeline.

__global__ __launch_bounds__(256) void agg1_kernel(const float* __restrict__ feat,
                                                   const float* __restrict__ el,
                                                   const float* __restrict__ er,
                                                   const int* __restrict__ rowptr,
                                                   const int* __restrict__ csrc,
                                                   const float* __restrict__ bias,
                                                   float* __restrict__ out, int N) {
    int lane = threadIdx.x & 63;
    int node = blockIdx.x * 4 + (threadIdx.x >> 6);
    if (node >= N) return;
    int row0 = __builtin_amdgcn_readfirstlane(rowptr[node]);
    int row1 = __builtin_amdgcn_readfirstlane(rowptr[node + 1]);

    float ern = er[node];
    int g = lane >> 3;
    int li = lane & 7;

    float dacc = 0.f;
    float acc[4];
#pragma unroll
    for (int r = 0; r < 4; ++r) acc[r] = 0.f;

    for (int base = row0; base < row1; base += 64) {
        int e = base + lane;
        int s = 0;
        float w0 = 0.f;
        if (e < row1) {
            s = csrc[e];
            float t0 = el[s] + ern;
            t0 = t0 > 0.f ? t0 : NEG_SLOPE * t0;
            w0 = __expf(t0);
            dacc += w0;
        }
        int cnt = min(row1 - base, 64);
        int iters = (cnt + 7) >> 3;
        int it = 0;
        for (; it + 1 < iters; it += 2) {
            int idxA = ((it << 3) + g) << 2;
            int idxB = (((it + 1) << 3) + g) << 2;
            int sjA = __builtin_amdgcn_ds_bpermute(idxA, s);
            float wA = bperm_f(idxA, w0);
            int sjB = __builtin_amdgcn_ds_bpermute(idxB, s);
            float wB = bperm_f(idxB, w0);
            const float4* fpA = (const float4*)(feat + (size_t)sjA * 32) + li;
            const float4* fpB = (const float4*)(feat + (size_t)sjB * 32) + li;
            float4 a0 = fpA[0], b0 = fpB[0];
            acc[0] = fmaf(wA, a0.x, acc[0]); acc[1] = fmaf(wA, a0.y, acc[1]);
            acc[2] = fmaf(wA, a0.z, acc[2]); acc[3] = fmaf(wA, a0.w, acc[3]);
            acc[0] = fmaf(wB, b0.x, acc[0]); acc[1] = fmaf(wB, b0.y, acc[1]);
            acc[2] = fmaf(wB, b0.z, acc[2]); acc[3] = fmaf(wB, b0.w, acc[3]);
        }
        if (it < iters) {
            int idx = ((it << 3) + g) << 2;
            int sj = __builtin_amdgcn_ds_bpermute(idx, s);
            float wsel = bperm_f(idx, w0);
            const float4* fp = (const float4*)(feat + (size_t)sj * 32) + li;
            float4 v0 = fp[0];
            acc[0] = fmaf(wsel, v0.x, acc[0]); acc[1] = fmaf(wsel, v0.y, acc[1]);
            acc[2] = fmaf(wsel, v0.z, acc[2]); acc[3] = fmaf(wsel, v0.w, acc[3]);
        }
    }

#pragma unroll
    for (int r = 0; r < 4; ++r) {
        acc[r] += __shfl_xor(acc[r], 8);
        acc[r] += __shfl_xor(acc[r], 16);
        acc[r] += __shfl_xor(acc[r], 32);
    }
#pragma unroll
    for (int off = 1; off < 64; off <<= 1) dacc += __shfl_xor(dacc, off);

    if (lane < 8) {
        float inv = (row1 > row0) ? 1.f / dacc : 0.f;
        float4 b0 = ((const float4*)bias)[lane];
        float4 q;
        q.x = acc[0] * inv + b0.x;
        q.y = acc[1] * inv + b0.y;
        q.z = acc[2] * inv + b0.z;
        q.w = acc[3] * inv + b0.w;
        ((float4*)(out + (size_t)node * 32))[lane] = q;
    }
}

// ---------------- host ----------------

extern "C" void kernel_launch(void* const* d_in, const int* in_sizes, int n_in,
                              void* d_out, int out_size, void* d_ws, size_t ws_size,
                              hipStream_t stream) {
    const float* features = (const float*)d_in[0];
    const int* esrc = (const int*)d_in[1];
    const int* edst = (const int*)d_in[2];
    const float* W1 = (const float*)d_in[3];
    const float* a1s = (const float*)d_in[4];
    const float* a1d = (const float*)d_in[5];
    const float* b1 = (const float*)d_in[6];
    const float* W2 = (const float*)d_in[7];
    const float* a2s = (const float*)d_in[8];
    const float* a2d = (const float*)d_in[9];
    const float* b2 = (const float*)d_in[10];
    const float* W3 = (const float*)d_in[11];
    const float* a3s = (const float*)d_in[12];
    const float* a3d = (const float*)d_in[13];
    const float* b3 = (const float*)d_in[14];

    int N = in_sizes[0] / 128;
    int E = in_sizes[1];
    int nb = (N + SCAN_CH - 1) / SCAN_CH;

    char* base = (char*)d_ws;
    size_t off = 0;
    auto nxt = [&](size_t bytes) {
        void* p = base + off;
        off += (bytes + 255) & ~(size_t)255;
        return p;
    };
    float* A = (float*)nxt((size_t)N * 128 * 4);   // feat
    float* B = (float*)nxt((size_t)N * 128 * 4);   // layer activations
    float* el = (float*)nxt((size_t)N * 4 * 4);
    float* er = (float*)nxt((size_t)N * 4 * 4);
    int* deg = (int*)nxt((size_t)N * 2 * 4);       // deg + cursor contiguous
    int* cursor = deg + N;
    int* rowptr = (int*)nxt((size_t)(N + 1) * 4);
    int* csrc = (int*)nxt((size_t)E * 4);
    int* bsum = (int*)nxt((size_t)(nb + 1) * 4);
    int* boff = (int*)nxt((size_t)(nb + 1) * 4);

    // CSR build (same graph for all 3 layers)
    zero_ints<<<(2 * N + 255) / 256, 256, 0, stream>>>(deg, 2 * N);
    hist_kernel<<<(E + 255) / 256, 256, 0, stream>>>(edst, deg, E);
    scan_blocksum<<<nb, 256, 0, stream>>>(deg, bsum, N);
    scan_bsum<<<1, 64, 0, stream>>>(bsum, boff, nb);
    scan_write<<<nb, 256, 0, stream>>>(deg, boff, rowptr, N);
    fill_kernel<<<(E + 255) / 256, 256, 0, stream>>>(esrc, edst, rowptr, cursor, csrc, E);

    // layer 1: 128 -> 4x32, ELU
    gemm_kernel<128><<<(N + 31) / 32, 256, 0, stream>>>(features, W1, A, a1s, a1d, el, er, N);
    agg4_kernel<true><<<(N + 3) / 4, 256, 0, stream>>>(A, el, er, rowptr, csrc, b1, B, N);

    // layer 2: 128 -> 4x32, ELU
    gemm_kernel<128><<<(N + 31) / 32, 256, 0, stream>>>(B, W2, A, a2s, a2d, el, er, N);
    agg4_kernel<true><<<(N + 3) / 4, 256, 0, stream>>>(A, el, er, rowptr, csrc, b2, B, N);

    // layer 3: 128 -> 1x32, no ELU, mean over 1 head = identity
    gemm_kernel<32><<<(N + 127) / 128, 256, 0, stream>>>(B, W3, A, a3s, a3d, el, er, N);
    agg1_kernel<<<(N + 3) / 4, 256, 0, stream>>>(A, el, er, rowptr, csrc, b3,
                                                 (float*)d_out, N);
}

// Round 9
// 315.853 us; speedup vs baseline: 1.4336x; 1.0084x over previous
//
#include <hip/hip_runtime.h>

#define NEG_SLOPE 0.2f

__device__ __forceinline__ float bperm_f(int idx, float v) {
    return __int_as_float(__builtin_amdgcn_ds_bpermute(idx, __float_as_int(v)));
}

// ---------------- CSR build ----------------

__global__ void zero_ints(int* __restrict__ p, int n) {
    int i = blockIdx.x * 256 + threadIdx.x;
    if (i < n) p[i] = 0;
}

__global__ void hist_kernel(const int* __restrict__ dst, int* __restrict__ deg, int E) {
    int i = blockIdx.x * 256 + threadIdx.x;
    if (i < E) atomicAdd(&deg[dst[i]], 1);
}

#define SCAN_CH 2048

__global__ __launch_bounds__(256) void scan_blocksum(const int* __restrict__ deg,
                                                     int* __restrict__ bsum, int N) {
    int blk = blockIdx.x, t = threadIdx.x;
    int base = blk * SCAN_CH;
    int s = 0;
#pragma unroll
    for (int i = 0; i < SCAN_CH / 256; ++i) {
        int idx = base + t + i * 256;
        if (idx < N) s += deg[idx];
    }
#pragma unroll
    for (int off = 1; off < 64; off <<= 1) s += __shfl_xor(s, off);
    __shared__ int wt[4];
    if ((t & 63) == 0) wt[t >> 6] = s;
    __syncthreads();
    if (t == 0) bsum[blk] = wt[0] + wt[1] + wt[2] + wt[3];
}

__global__ void scan_bsum(const int* __restrict__ bsum, int* __restrict__ boff, int nb) {
    int t = threadIdx.x;
    int orig = (t < nb) ? bsum[t] : 0;
    int v = orig;
#pragma unroll
    for (int off = 1; off < 64; off <<= 1) {
        int u = __shfl_up(v, off);
        if (t >= off) v += u;
    }
    if (t < nb) boff[t] = v - orig;
}

__global__ __launch_bounds__(256) void scan_write(const int* __restrict__ deg,
                                                  const int* __restrict__ boff,
                                                  int* __restrict__ rowptr, int N) {
    int blk = blockIdx.x, t = threadIdx.x;
    int base = blk * SCAN_CH + t * 8;
    int v[8];
    int s = 0;
#pragma unroll
    for (int r = 0; r < 8; ++r) {
        int idx = base + r;
        v[r] = (idx < N) ? deg[idx] : 0;
        s += v[r];
    }
    int lane = t & 63, wid = t >> 6;
    int p = s;
#pragma unroll
    for (int off = 1; off < 64; off <<= 1) {
        int u = __shfl_up(p, off);
        if (lane >= off) p += u;
    }
    __shared__ int wtot[4];
    if (lane == 63) wtot[wid] = p;
    __syncthreads();
    int run = boff[blk];
    for (int w = 0; w < wid; ++w) run += wtot[w];
    run += p - s;
#pragma unroll
    for (int r = 0; r < 8; ++r) {
        int idx = base + r;
        if (idx < N) {
            rowptr[idx] = run;
            run += v[r];
            if (idx == N - 1) rowptr[N] = run;
        }
    }
}

__global__ void fill_kernel(const int* __restrict__ src, const int* __restrict__ dst,
                            const int* __restrict__ rowptr, int* __restrict__ cursor,
                            int* __restrict__ csrc, int E) {
    int i = blockIdx.x * 256 + threadIdx.x;
    if (i < E) {
        int d = dst[i];
        int pos = atomicAdd(&cursor[d], 1);
        csrc[rowptr[d] + pos] = src[i];
    }
}

// -------- GEMM + fused el/er: Y = X@W;  el/er = (Y reshaped).dot(a_s/a_d) --------

template <int OUTF>
__global__ __launch_bounds__(256) void gemm_kernel(const float* __restrict__ X,
                                                   const float* __restrict__ W,
                                                   float* __restrict__ Y,
                                                   const float* __restrict__ as_,
                                                   const float* __restrict__ ad_,
                                                   float* __restrict__ el,
                                                   float* __restrict__ er, int N) {
    constexpr int K = 128;
    constexpr int MG = OUTF / 4;          // thread-groups along M
    constexpr int NPB = (256 / MG) * 4;   // nodes per block
    constexpr int H = OUTF / 32;          // heads
    __shared__ float ws[K * OUTF];
    __shared__ float xs[NPB * K];
    int t = threadIdx.x;
    int nbase = blockIdx.x * NPB;

    {   // stage W
        const float4* Wg = (const float4*)W;
        float4* wl = (float4*)ws;
        constexpr int WIT = K * OUTF / 4 / 256;
#pragma unroll
        for (int i = 0; i < WIT; ++i) wl[t + i * 256] = Wg[t + i * 256];
    }
    {   // stage X rows
        const float4* Xg = (const float4*)X;
        float4* xl = (float4*)xs;
        constexpr int XIT = NPB * K / 4 / 256;
#pragma unroll
        for (int i = 0; i < XIT; ++i) {
            int idx = t + i * 256;
            int n = idx >> 5, kq = idx & 31;
            int gn = nbase + n;
            gn = min(gn, N - 1);
            xl[idx] = Xg[(size_t)gn * 32 + kq];
        }
    }
    __syncthreads();

    int mg = t % MG, ngq = t / MG;
    int n0 = ngq * 4;
    float acc[4][4];
#pragma unroll
    for (int i = 0; i < 4; ++i)
#pragma unroll
        for (int j = 0; j < 4; ++j) acc[i][j] = 0.f;

    const float4* xsv = (const float4*)xs;
    const float4* wsv = (const float4*)ws;
    for (int k = 0; k < K; k += 4) {
        float4 xv[4], wv[4];
#pragma unroll
        for (int i = 0; i < 4; ++i) xv[i] = xsv[(n0 + i) * 32 + (k >> 2)];
#pragma unroll
        for (int kk = 0; kk < 4; ++kk) wv[kk] = wsv[(k + kk) * MG + mg];
#pragma unroll
        for (int i = 0; i < 4; ++i) {
#pragma unroll
            for (int kk = 0; kk < 4; ++kk) {
                float xf = ((const float*)&xv[i])[kk];
                acc[i][0] = fmaf(xf, wv[kk].x, acc[i][0]);
                acc[i][1] = fmaf(xf, wv[kk].y, acc[i][1]);
                acc[i][2] = fmaf(xf, wv[kk].z, acc[i][2]);
                acc[i][3] = fmaf(xf, wv[kk].w, acc[i][3]);
            }
        }
    }

    // fused attention logits: head h = mg/8 (H=4) or 0 (H=1)
    int h = mg >> 3;
    if (OUTF == 32) h = 0;
    float4 as4 = ((const float4*)as_)[mg];
    float4 ad4 = ((const float4*)ad_)[mg];

    float4* Yg = (float4*)Y;
#pragma unroll
    for (int i = 0; i < 4; ++i) {
        int gn = nbase + n0 + i;
        float pel = acc[i][0] * as4.x + acc[i][1] * as4.y + acc[i][2] * as4.z +
                    acc[i][3] * as4.w;
        float per = acc[i][0] * ad4.x + acc[i][1] * ad4.y + acc[i][2] * ad4.z +
                    acc[i][3] * ad4.w;
#pragma unroll
        for (int off = 1; off < 8; off <<= 1) {
            pel += __shfl_xor(pel, off);
            per += __shfl_xor(per, off);
        }
        if (gn < N) {
            float4 r;
            r.x = acc[i][0]; r.y = acc[i][1]; r.z = acc[i][2]; r.w = acc[i][3];
            Yg[(size_t)gn * MG + mg] = r;
            if ((mg & 7) == 0) {
                el[gn * H + h] = pel;
                er[gn * H + h] = per;
            }
        }
    }
}

// ---------------- aggregation (H=4): one wave per dst node ----------------
// Weight phase: 16-edge batches, lane m handles edge m>>2, head m&3.
// Gather: straight-line 4 iterations (no inner loop): 8 bpermutes -> 8
// global_load_dwordx4 in flight -> 64 fmas. Over-read iterations carry w=0.

template <bool DOELU>
__global__ __launch_bounds__(256) void agg4_kernel(const float* __restrict__ feat,
                                                   const float* __restrict__ el,
                                                   const float* __restrict__ er,
                                                   const int* __restrict__ rowptr,
                                                   const int* __restrict__ csrc,
                                                   const float* __restrict__ bias,
                                                   float* __restrict__ out, int N) {
    int lane = threadIdx.x & 63;
    int node = blockIdx.x * 4 + (threadIdx.x >> 6);
    if (node >= N) return;
    int row0 = __builtin_amdgcn_readfirstlane(rowptr[node]);
    int row1 = __builtin_amdgcn_readfirstlane(rowptr[node + 1]);

    int qe = lane >> 2;       // edge slot in 16-edge batch
    int qh = lane & 3;        // head for weight phase
    float ern = er[node * 4 + qh];

    int g = lane >> 4;        // gather group
    int li = lane & 15;       // lane in group: feats li*8..li*8+7
    int h = li >> 2;          // head owning those feats
    int ib = (g << 4) + (h << 2);  // bpermute byte base: lane (g*4+h) of iter 0

    float dacc = 0.f;
    float acc[8];
#pragma unroll
    for (int r = 0; r < 8; ++r) acc[r] = 0.f;

    for (int base = row0; base < row1; base += 16) {
        int e = base + qe;
        int s = 0;
        float w = 0.f;
        if (e < row1) {
            s = csrc[e];
            float tt = el[s * 4 + qh] + ern;
            tt = tt > 0.f ? tt : NEG_SLOPE * tt;
            w = __expf(tt);
            dacc += w;
        }
        // all 4 gather iterations, fully unrolled
        int sj0 = __builtin_amdgcn_ds_bpermute(ib, s);
        float w0 = bperm_f(ib, w);
        int sj1 = __builtin_amdgcn_ds_bpermute(ib + 64, s);
        float w1 = bperm_f(ib + 64, w);
        int sj2 = __builtin_amdgcn_ds_bpermute(ib + 128, s);
        float w2 = bperm_f(ib + 128, w);
        int sj3 = __builtin_amdgcn_ds_bpermute(ib + 192, s);
        float w3 = bperm_f(ib + 192, w);
        const float4* f0 = (const float4*)(feat + (size_t)sj0 * 128) + li * 2;
        const float4* f1 = (const float4*)(feat + (size_t)sj1 * 128) + li * 2;
        const float4* f2 = (const float4*)(feat + (size_t)sj2 * 128) + li * 2;
        const float4* f3 = (const float4*)(feat + (size_t)sj3 * 128) + li * 2;
        float4 a0 = f0[0], a1 = f0[1];
        float4 b0 = f1[0], b1 = f1[1];
        float4 c0 = f2[0], c1 = f2[1];
        float4 d0 = f3[0], d1 = f3[1];
        acc[0] = fmaf(w0, a0.x, acc[0]); acc[1] = fmaf(w0, a0.y, acc[1]);
        acc[2] = fmaf(w0, a0.z, acc[2]); acc[3] = fmaf(w0, a0.w, acc[3]);
        acc[4] = fmaf(w0, a1.x, acc[4]); acc[5] = fmaf(w0, a1.y, acc[5]);
        acc[6] = fmaf(w0, a1.z, acc[6]); acc[7] = fmaf(w0, a1.w, acc[7]);
        acc[0] = fmaf(w1, b0.x, acc[0]); acc[1] = fmaf(w1, b0.y, acc[1]);
        acc[2] = fmaf(w1, b0.z, acc[2]); acc[3] = fmaf(w1, b0.w, acc[3]);
        acc[4] = fmaf(w1, b1.x, acc[4]); acc[5] = fmaf(w1, b1.y, acc[5]);
        acc[6] = fmaf(w1, b1.z, acc[6]); acc[7] = fmaf(w1, b1.w, acc[7]);
        acc[0] = fmaf(w2, c0.x, acc[0]); acc[1] = fmaf(w2, c0.y, acc[1]);
        acc[2] = fmaf(w2, c0.z, acc[2]); acc[3] = fmaf(w2, c0.w, acc[3]);
        acc[4] = fmaf(w2, c1.x, acc[4]); acc[5] = fmaf(w2, c1.y, acc[5]);
        acc[6] = fmaf(w2, c1.z, acc[6]); acc[7] = fmaf(w2, c1.w, acc[7]);
        acc[0] = fmaf(w3, d0.x, acc[0]); acc[1] = fmaf(w3, d0.y, acc[1]);
        acc[2] = fmaf(w3, d0.z, acc[2]); acc[3] = fmaf(w3, d0.w, acc[3]);
        acc[4] = fmaf(w3, d1.x, acc[4]); acc[5] = fmaf(w3, d1.y, acc[5]);
        acc[6] = fmaf(w3, d1.z, acc[6]); acc[7] = fmaf(w3, d1.w, acc[7]);
    }

    // reduce partial rows across the 4 gather groups
#pragma unroll
    for (int r = 0; r < 8; ++r) {
        acc[r] += __shfl_xor(acc[r], 16);
        acc[r] += __shfl_xor(acc[r], 32);
    }
    // denominator: sum over all lanes sharing the same head (lane&3)
#pragma unroll
    for (int off = 4; off < 64; off <<= 1) dacc += __shfl_xor(dacc, off);
    float d = bperm_f((li >> 2) << 2, dacc);

    if (lane < 16) {
        float inv = (row1 > row0) ? 1.f / d : 0.f;
        const float4* bv = (const float4*)bias + li * 2;
        float4 b0 = bv[0], b1 = bv[1];
        float o[8];
#pragma unroll
        for (int r = 0; r < 8; ++r) o[r] = acc[r] * inv;
        o[0] += b0.x; o[1] += b0.y; o[2] += b0.z; o[3] += b0.w;
        o[4] += b1.x; o[5] += b1.y; o[6] += b1.z; o[7] += b1.w;
        if (DOELU) {
#pragma unroll
            for (int r = 0; r < 8; ++r) o[r] = o[r] > 0.f ? o[r] : __expf(o[r]) - 1.f;
        }
        float4 q0, q1;
        q0.x = o[0]; q0.y = o[1]; q0.z = o[2]; q0.w = o[3];
        q1.x = o[4]; q1.y = o[5]; q1.z = o[6]; q1.w = o[7];
        float4* ov = (float4*)(out + (size_t)node * 128) + li * 2;
        ov[0] = q0;
        ov[1] = q1;
    }
}

// ---------------- aggregation (H=1): one wave per dst node ----------------

__global__ __launch_bounds__(256) void agg1_kernel(const float* __restrict__ feat,
                                                   const float* __restrict__ el,
                                                   const float* __restrict__ er,
                                                   const int* __restrict__ rowptr,
                                                   const int* __restrict__ csrc,
                                                   const float* __restrict__ bias,
                                                   float* __restrict__ out, int N) {
    int lane = threadIdx.x & 63;
    int node = blockIdx.x * 4 + (threadIdx.x >> 6);
    if (node >= N) return;
    int row0 = __builtin_amdgcn_readfirstlane(rowptr[node]);
    int row1 = __builtin_amdgcn_readfirstlane(rowptr[node + 1]);

    float ern = er[node];
    int g = lane >> 3;
    int li = lane & 7;

    float dacc = 0.f;
    float acc[4];
#pragma unroll
    for (int r = 0; r < 4; ++r) acc[r] = 0.f;

    for (int base = row0; base < row1; base += 64) {
        int e = base + lane;
        int s = 0;
        float w0 = 0.f;
        if (e < row1) {
            s = csrc[e];
            float t0 = el[s] + ern;
            t0 = t0 > 0.f ? t0 : NEG_SLOPE * t0;
            w0 = __expf(t0);
            dacc += w0;
        }
        int cnt = min(row1 - base, 64);
        int iters = (cnt + 7) >> 3;
        int it = 0;
        for (; it + 1 < iters; it += 2) {
            int idxA = ((it << 3) + g) << 2;
            int idxB = (((it + 1) << 3) + g) << 2;
            int sjA = __builtin_amdgcn_ds_bpermute(idxA, s);
            float wA = bperm_f(idxA, w0);
            int sjB = __builtin_amdgcn_ds_bpermute(idxB, s);
            float wB = bperm_f(idxB, w0);
            const float4* fpA = (const float4*)(feat + (size_t)sjA * 32) + li;
            const float4* fpB = (const float4*)(feat + (size_t)sjB * 32) + li;
            float4 a0 = fpA[0], b0 = fpB[0];
            acc[0] = fmaf(wA, a0.x, acc[0]); acc[1] = fmaf(wA, a0.y, acc[1]);
            acc[2] = fmaf(wA, a0.z, acc[2]); acc[3] = fmaf(wA, a0.w, acc[3]);
            acc[0] = fmaf(wB, b0.x, acc[0]); acc[1] = fmaf(wB, b0.y, acc[1]);
            acc[2] = fmaf(wB, b0.z, acc[2]); acc[3] = fmaf(wB, b0.w, acc[3]);
        }
        if (it < iters) {
            int idx = ((it << 3) + g) << 2;
            int sj = __builtin_amdgcn_ds_bpermute(idx, s);
            float wsel = bperm_f(idx, w0);
            const float4* fp = (const float4*)(feat + (size_t)sj * 32) + li;
            float4 v0 = fp[0];
            acc[0] = fmaf(wsel, v0.x, acc[0]); acc[1] = fmaf(wsel, v0.y, acc[1]);
            acc[2] = fmaf(wsel, v0.z, acc[2]); acc[3] = fmaf(wsel, v0.w, acc[3]);
        }
    }

#pragma unroll
    for (int r = 0; r < 4; ++r) {
        acc[r] += __shfl_xor(acc[r], 8);
        acc[r] += __shfl_xor(acc[r], 16);
        acc[r] += __shfl_xor(acc[r], 32);
    }
#pragma unroll
    for (int off = 1; off < 64; off <<= 1) dacc += __shfl_xor(dacc, off);

    if (lane < 8) {
        float inv = (row1 > row0) ? 1.f / dacc : 0.f;
        float4 b0 = ((const float4*)bias)[lane];
        float4 q;
        q.x = acc[0] * inv + b0.x;
        q.y = acc[1] * inv + b0.y;
        q.z = acc[2] * inv + b0.z;
        q.w = acc[3] * inv + b0.w;
        ((float4*)(out + (size_t)node * 32))[lane] = q;
    }
}

// ---------------- host ----------------

extern "C" void kernel_launch(void* const* d_in, const int* in_sizes, int n_in,
                              void* d_out, int out_size, void* d_ws, size_t ws_size,
                              hipStream_t stream) {
    const float* features = (const float*)d_in[0];
    const int* esrc = (const int*)d_in[1];
    const int* edst = (const int*)d_in[2];
    const float* W1 = (const float*)d_in[3];
    const float* a1s = (const float*)d_in[4];
    const float* a1d = (const float*)d_in[5];
    const float* b1 = (const float*)d_in[6];
    const float* W2 = (const float*)d_in[7];
    const float* a2s = (const float*)d_in[8];
    const float* a2d = (const float*)d_in[9];
    const float* b2 = (const float*)d_in[10];
    const float* W3 = (const float*)d_in[11];
    const float* a3s = (const float*)d_in[12];
    const float* a3d = (const float*)d_in[13];
    const float* b3 = (const float*)d_in[14];

    int N = in_sizes[0] / 128;
    int E = in_sizes[1];
    int nb = (N + SCAN_CH - 1) / SCAN_CH;

    char* base = (char*)d_ws;
    size_t off = 0;
    auto nxt = [&](size_t bytes) {
        void* p = base + off;
        off += (bytes + 255) & ~(size_t)255;
        return p;
    };
    float* A = (float*)nxt((size_t)N * 128 * 4);   // feat
    float* B = (float*)nxt((size_t)N * 128 * 4);   // layer activations
    float* el = (float*)nxt((size_t)N * 4 * 4);
    float* er = (float*)nxt((size_t)N * 4 * 4);
    int* deg = (int*)nxt((size_t)N * 2 * 4);       // deg + cursor contiguous
    int* cursor = deg + N;
    int* rowptr = (int*)nxt((size_t)(N + 1) * 4);
    int* csrc = (int*)nxt((size_t)E * 4);
    int* bsum = (int*)nxt((size_t)(nb + 1) * 4);
    int* boff = (int*)nxt((size_t)(nb + 1) * 4);

    // CSR build (same graph for all 3 layers)
    zero_ints<<<(2 * N + 255) / 256, 256, 0, stream>>>(deg, 2 * N);
    hist_kernel<<<(E + 255) / 256, 256, 0, stream>>>(edst, deg, E);
    scan_blocksum<<<nb, 256, 0, stream>>>(deg, bsum, N);
    scan_bsum<<<1, 64, 0, stream>>>(bsum, boff, nb);
    scan_write<<<nb, 256, 0, stream>>>(deg, boff, rowptr, N);
    fill_kernel<<<(E + 255) / 256, 256, 0, stream>>>(esrc, edst, rowptr, cursor, csrc, E);

    // layer 1: 128 -> 4x32, ELU
    gemm_kernel<128><<<(N + 31) / 32, 256, 0, stream>>>(features, W1, A, a1s, a1d, el, er, N);
    agg4_kernel<true><<<(N + 3) / 4, 256, 0, stream>>>(A, el, er, rowptr, csrc, b1, B, N);

    // layer 2: 128 -> 4x32, ELU
    gemm_kernel<128><<<(N + 31) / 32, 256, 0, stream>>>(B, W2, A, a2s, a2d, el, er, N);
    agg4_kernel<true><<<(N + 3) / 4, 256, 0, stream>>>(A, el, er, rowptr, csrc, b2, B, N);

    // layer 3: 128 -> 1x32, no ELU, mean over 1 head = identity
    gemm_kernel<32><<<(N + 127) / 128, 256, 0, stream>>>(B, W3, A, a3s, a3d, el, er, N);
    agg1_kernel<<<(N + 3) / 4, 256, 0, stream>>>(A, el, er, rowptr, csrc, b3,
                                                 (float*)d_out, N);
}